// Round 3
// baseline (1207.094 us; speedup 1.0000x reference)
//
#include <hip/hip_runtime.h>
#include <stdint.h>

// SparseExpertRouter: B=4 S=2048 D=1024 H=4096 R=512 E=8 TOPK=2
// Pipeline:
//   1) W1,W2 -> bf16 ; x,Wr1 -> 3-term hi/lo split (K=3072, fp32-accurate router GEMM)
//      x3 = [x_hi, x_lo, x_hi], w3 = [w_hi, w_hi, w_lo]
//      => dot = hi.hi + lo.hi + hi.lo  (residual ~2^-18)
//   2) router GEMM (MODE 2): h = gelu(x3 @ w3^T + br1)  [8192,512] fp32
//   3) router_topk: logits -> softmax -> top2 -> per-expert lists (atomic append)
//   4) expert GEMM1 (MODE 0, gathered tokens rid>>1): he[rid] = gelu(x_hi @ W1[e]^T + b1[e]) bf16
//   5) expert GEMM2 (MODE 1, gathered he rows rid): out[rid>>1] += w * (he @ W2[e]^T + b2[e])

#define T_TOK 8192
#define NE 8

typedef float  floatx4 __attribute__((ext_vector_type(4)));
typedef short  shortx8 __attribute__((ext_vector_type(8)));

__device__ __forceinline__ unsigned short f2bf(float f) {
  union { float f; unsigned int u; } a; a.f = f;
  unsigned int r = ((a.u >> 16) & 1u) + 0x7fffu;   // round-to-nearest-even
  return (unsigned short)((a.u + r) >> 16);
}
__device__ __forceinline__ float bf2f(unsigned short s) {
  union { unsigned int u; float f; } a; a.u = ((unsigned int)s) << 16;
  return a.f;
}
__device__ __forceinline__ float gelu_exact(float v) {
  return 0.5f * v * (1.0f + erff(v * 0.7071067811865475f));
}
// async global->LDS, 16B per lane. LDS dest is wave-uniform base + lane*16.
__device__ __forceinline__ void load_lds16(const void* g, void* l) {
  __builtin_amdgcn_global_load_lds(
      (const __attribute__((address_space(1))) void*)(uintptr_t)g,
      (__attribute__((address_space(3))) unsigned int*)(uint32_t)(uintptr_t)l,
      16, 0, 0);
}

// ---------------- conversions ----------------
__global__ void __launch_bounds__(256)
to_bf16(const float* __restrict__ src, unsigned short* __restrict__ dst, long n8) {
  long i = (long)blockIdx.x * 256 + threadIdx.x;
  if (i >= n8) return;
  const float4* s = (const float4*)src + i * 2;
  float4 a = s[0], b = s[1];
  union { shortx8 v; unsigned short u[8]; } o;
  o.u[0] = f2bf(a.x); o.u[1] = f2bf(a.y); o.u[2] = f2bf(a.z); o.u[3] = f2bf(a.w);
  o.u[4] = f2bf(b.x); o.u[5] = f2bf(b.y); o.u[6] = f2bf(b.z); o.u[7] = f2bf(b.w);
  ((shortx8*)dst)[i] = o.v;
}

// src [rows][cols] fp32 -> dst [rows][3*cols] bf16.
// hi written at ushort4-col {c4} and {hiOff+c4}; lo at {loOff+c4}. Offsets in ushort4 units.
__global__ void __launch_bounds__(256)
split3_bf16(const float* __restrict__ src, unsigned short* __restrict__ dst,
            int cols4, int hiOff, int loOff, long n4) {
  long i = (long)blockIdx.x * 256 + threadIdx.x;
  if (i >= n4) return;
  long r = i / cols4; int c4 = (int)(i % cols4);
  float4 a = ((const float4*)src)[i];
  float f[4] = {a.x, a.y, a.z, a.w};
  union { ushort4 v; unsigned short u[4]; } hi, lo;
#pragma unroll
  for (int j = 0; j < 4; j++) {
    hi.u[j] = f2bf(f[j]);
    lo.u[j] = f2bf(f[j] - bf2f(hi.u[j]));
  }
  ushort4* drow = (ushort4*)(dst + r * 3l * (cols4 * 4));
  drow[c4]         = hi.v;
  drow[hiOff + c4] = hi.v;
  drow[loOff + c4] = lo.v;
}

// ---------------- router finish: logits -> softmax -> top2 -> lists ----------------
__global__ void __launch_bounds__(256)
router_topk(const float* __restrict__ h, const float* __restrict__ Wr2,
            const float* __restrict__ br2, int* __restrict__ cnt,
            int* __restrict__ list, float* __restrict__ wrow) {
  const int lane = threadIdx.x & 63;
  const int t = blockIdx.x * 4 + (threadIdx.x >> 6);
  const int e = lane >> 3, seg = lane & 7;  // lanes [8e..8e+7] handle expert e, h-chunk seg*64
  const float4* hp = (const float4*)(h + (long)t * 512 + seg * 64);
  const float4* wp = (const float4*)(Wr2 + e * 512 + seg * 64);
  float s = 0.f;
#pragma unroll
  for (int j = 0; j < 16; j++) {
    float4 a = hp[j], b = wp[j];
    s += a.x * b.x + a.y * b.y + a.z * b.z + a.w * b.w;
  }
  s += __shfl_xor(s, 1); s += __shfl_xor(s, 2); s += __shfl_xor(s, 4);
  float lg[8];
#pragma unroll
  for (int k = 0; k < 8; k++) lg[k] = __shfl(s, k * 8) + br2[k];
  float mx = lg[0];
#pragma unroll
  for (int k = 1; k < 8; k++) mx = fmaxf(mx, lg[k]);
  float se = 0.f;
#pragma unroll
  for (int k = 0; k < 8; k++) se += expf(lg[k] - mx);
  int i0 = 0; float v0 = lg[0];
#pragma unroll
  for (int k = 1; k < 8; k++) if (lg[k] > v0) { v0 = lg[k]; i0 = k; }
  int i1 = -1; float v1 = -1e30f;
#pragma unroll
  for (int k = 0; k < 8; k++) if (k != i0 && lg[k] > v1) { v1 = lg[k]; i1 = k; }
  if (lane == 0) {
    float w0 = expf(v0 - mx) / se, w1 = expf(v1 - mx) / se;
    int p0 = atomicAdd(&cnt[i0], 1);
    list[i0 * T_TOK + p0] = 2 * t;       // he-row id encodes (token, slot)
    wrow[2 * t] = w0;
    int p1 = atomicAdd(&cnt[i1], 1);
    list[i1 * T_TOK + p1] = 2 * t + 1;
    wrow[2 * t + 1] = w1;
  }
}

// ---------------- MFMA GEMM, 128x128 tile, BK=32, 4 waves ----------------
// MODE 0: expert GEMM1  (gather A rows = rowid>>1 (token); epilogue gelu -> bf16 he[rid])
// MODE 1: expert GEMM2  (gather A rows = rowid (he row); epilogue w*(acc+b2) atomicAdd out[rid>>1])
// MODE 2: router GEMM   (dense A; epilogue gelu -> fp32 h)
template <int MODE>
__global__ void __launch_bounds__(256)
gemm_mfma(const unsigned short* __restrict__ Abase, int Astride,
          const unsigned short* __restrict__ Bbase, long Bestride, int Bstride,
          const float* __restrict__ biasBase, int biasStride,
          const int* __restrict__ listBase, const int* __restrict__ cnt,
          const float* __restrict__ wrow,
          float* __restrict__ outF, unsigned short* __restrict__ outH,
          long outStride, int Ntiles, int K) {
  const int e  = blockIdx.y;
  const int mt = blockIdx.x / Ntiles;
  const int nt = blockIdx.x % Ntiles;
  int M;
  const int* list = nullptr;
  if (MODE == 2) {
    M = T_TOK;
  } else {
    M = cnt[e];
    list = listBase + e * T_TOK;
  }
  if (mt * 128 >= M) return;

  __shared__ alignas(16) short As[128 * 32];
  __shared__ alignas(16) short Bs[128 * 32];
  __shared__ int rowid[128];

  const int tid = threadIdx.x;
  const int lane = tid & 63;
  const int w = tid >> 6;

  if (MODE != 2) {
    if (tid < 128) {
      int gi = mt * 128 + tid;
      rowid[tid] = list[(gi < M) ? gi : (M - 1)];  // clamp; stores masked below
    }
  }
  __syncthreads();

  // staging: wave w loads rows [w*16, w*16+16) (chunk 0) and +64 (chunk 1); 16B per lane
  const int ra0 = w * 16 + (lane >> 2);
  const int ra1 = 64 + ra0;
  long arow0, arow1;
  if (MODE == 2)      { arow0 = mt * 128 + ra0;  arow1 = mt * 128 + ra1; }
  else if (MODE == 0) { arow0 = rowid[ra0] >> 1; arow1 = rowid[ra1] >> 1; }  // token id
  else                { arow0 = rowid[ra0];      arow1 = rowid[ra1]; }       // he row id
  const char* ap0 = (const char*)Abase + arow0 * (long)Astride * 2 + (lane & 3) * 16;
  const char* ap1 = (const char*)Abase + arow1 * (long)Astride * 2 + (lane & 3) * 16;
  const unsigned short* Be = Bbase + (MODE == 2 ? 0 : e * Bestride);
  const int rb = nt * 128 + w * 16 + (lane >> 2);
  const char* bp0 = (const char*)Be + (long)rb * Bstride * 2 + (lane & 3) * 16;
  const char* bp1 = (const char*)Be + (long)(rb + 64) * Bstride * 2 + (lane & 3) * 16;

  char* ldsA = (char*)As + w * 1024;
  char* ldsB = (char*)Bs + w * 1024;

  // wave (wm,wn) owns 64x64 sub-tile; frags 16x16; A row=lane&15, B col=lane&15, k=(lane>>4)*8+j
  const int wm = w >> 1, wn = w & 1;
  const int aoff = (wm * 64 + (lane & 15)) * 32 + (lane >> 4) * 8;  // shorts
  const int boff = (wn * 64 + (lane & 15)) * 32 + (lane >> 4) * 8;

  floatx4 acc[4][4] = {};

  for (int ks = 0; ks < K; ks += 32) {
    if (ks) __syncthreads();
    load_lds16(ap0, ldsA);
    load_lds16(ap1, ldsA + 4096);
    load_lds16(bp0, ldsB);
    load_lds16(bp1, ldsB + 4096);
    ap0 += 64; ap1 += 64; bp0 += 64; bp1 += 64;
    __syncthreads();  // vmcnt(0) drain + barrier
    shortx8 af[4], bf[4];
#pragma unroll
    for (int mi = 0; mi < 4; mi++) af[mi] = *(const shortx8*)(As + aoff + mi * 512);
#pragma unroll
    for (int ni = 0; ni < 4; ni++) bf[ni] = *(const shortx8*)(Bs + boff + ni * 512);
#pragma unroll
    for (int mi = 0; mi < 4; mi++)
#pragma unroll
      for (int ni = 0; ni < 4; ni++)
        acc[mi][ni] = __builtin_amdgcn_mfma_f32_16x16x32_bf16(af[mi], bf[ni], acc[mi][ni], 0, 0, 0);
  }

  // epilogue; C/D: col=lane&15, row=(lane>>4)*4+reg (m89-verified)
  const float* bias = biasBase + (MODE == 2 ? 0 : (long)e * biasStride);
#pragma unroll
  for (int mi = 0; mi < 4; mi++) {
#pragma unroll
    for (int ni = 0; ni < 4; ni++) {
      const int c = nt * 128 + wn * 64 + ni * 16 + (lane & 15);
      const float bv = bias[c];
#pragma unroll
      for (int r = 0; r < 4; r++) {
        const int it = wm * 64 + mi * 16 + (lane >> 4) * 4 + r;  // row within tile
        const int gi = mt * 128 + it;
        if (MODE == 2) {
          outF[(long)gi * outStride + c] = gelu_exact(acc[mi][ni][r] + bv);
        } else if (gi < M) {
          const int rid = rowid[it];
          if (MODE == 0) {
            outH[(long)rid * outStride + c] = f2bf(gelu_exact(acc[mi][ni][r] + bv));
          } else {
            const float wgt = wrow[rid];
            atomicAdd(&outF[(long)(rid >> 1) * outStride + c], wgt * (acc[mi][ni][r] + bv));
          }
        }
      }
    }
  }
}

// ---------------- launch ----------------
extern "C" void kernel_launch(void* const* d_in, const int* in_sizes, int n_in,
                              void* d_out, int out_size, void* d_ws, size_t ws_size,
                              hipStream_t stream) {
  const float* x   = (const float*)d_in[0];
  const float* Wr1 = (const float*)d_in[1];
  const float* br1 = (const float*)d_in[2];
  const float* Wr2 = (const float*)d_in[3];
  const float* br2 = (const float*)d_in[4];
  const float* W1  = (const float*)d_in[5];
  const float* b1  = (const float*)d_in[6];
  const float* W2  = (const float*)d_in[7];
  const float* b2  = (const float*)d_in[8];
  float* out = (float*)d_out;

  char* ws = (char*)d_ws;
  unsigned short* xsplit = (unsigned short*)(ws);                 // [8192][3072] hi|lo|hi
  unsigned short* wr1s   = (unsigned short*)(ws + 50331648);      // [512][3072]  hi|hi|lo
  unsigned short* W1bf   = (unsigned short*)(ws + 53477376);      // [8][4096][1024]
  unsigned short* W2bf   = (unsigned short*)(ws + 120586240);     // [8][1024][4096]
  float*          h      = (float*)(ws + 187695104);              // [8192][512]
  unsigned short* he     = (unsigned short*)(ws + 204472320);     // [16384][4096]
  int*            list   = (int*)(ws + 338690048);                // [8][8192]
  float*          wrow   = (float*)(ws + 338952192);              // [16384]
  int*            cnt    = (int*)(ws + 339017728);                // [8]

  hipMemsetAsync(d_out, 0, (size_t)8192 * 1024 * 4, stream);
  hipMemsetAsync(cnt, 0, 256, stream);

  to_bf16<<<16384, 256, 0, stream>>>(W1, W1bf, 33554432 / 8);
  to_bf16<<<16384, 256, 0, stream>>>(W2, W2bf, 33554432 / 8);
  // x3 = [hi, lo, hi]: hi dup at 2*cols4, lo at cols4
  split3_bf16<<<8192, 256, 0, stream>>>(x, xsplit, 256, 512, 256, 2097152);
  // w3 = [hi, hi, lo]: hi dup at cols4, lo at 2*cols4
  split3_bf16<<<512, 256, 0, stream>>>(Wr1, wr1s, 256, 256, 512, 131072);

  // router GEMM: M=8192 N=512 K=3072 (3-term split -> fp32-accurate)
  gemm_mfma<2><<<dim3(64 * 4, 1), 256, 0, stream>>>(
      xsplit, 3072, wr1s, 0, 3072, br1, 0,
      nullptr, nullptr, nullptr, h, nullptr, 512, 4, 3072);

  router_topk<<<2048, 256, 0, stream>>>(h, Wr2, br2, cnt, list, wrow);

  // expert GEMM1: gathered tokens, N=4096, K=1024 (bf16 hi part of xsplit, row stride 3072)
  gemm_mfma<0><<<dim3(64 * 32, 8), 256, 0, stream>>>(
      xsplit, 3072, W1bf, (long)4096 * 1024, 1024, b1, 4096,
      list, cnt, nullptr, nullptr, he, 4096, 32, 1024);

  // expert GEMM2: gathered he rows, N=1024, K=4096; weighted atomicAdd into out
  gemm_mfma<1><<<dim3(64 * 8, 8), 256, 0, stream>>>(
      he, 4096, W2bf, (long)1024 * 4096, 4096, b2, 1024,
      list, cnt, wrow, out, nullptr, 1024, 8, 4096);
}